// Round 5
// baseline (422.435 us; speedup 1.0000x reference)
//
#include <hip/hip_runtime.h>
#include <hip/hip_bf16.h>

// GraphSAGE 3-layer forward.
// CSR build -> prep planes -> 3x fused k_sage:
//   phase1: gather bf16 hi-plane rows, fp32 mean, hi/lo planes into LDS
//   phase2: MFMA bf16x3 GEMM, self-K from global planes (GLDS), neigh-K from
//           phase-1 LDS. Epilogue emits next layer's hi/lo planes.

#define THREADS 256

typedef unsigned short u16;
typedef __attribute__((ext_vector_type(8))) short bf16x8;
typedef __attribute__((ext_vector_type(4))) float f32x4;

__device__ inline u16 f2bf(float f) {
    union { float f; unsigned u; } v; v.f = f;
    unsigned r = (v.u + 0x7FFFu + ((v.u >> 16) & 1u)) >> 16;
    return (u16)r;
}
__device__ inline float bf2f(u16 b) {
    union { unsigned u; float f; } v; v.u = ((unsigned)b) << 16;
    return v.f;
}
__device__ inline unsigned pack2(float a, float b) {
    return (unsigned)f2bf(a) | ((unsigned)f2bf(b) << 16);
}

#define GLDS16(gp, lp)                                                         \
    __builtin_amdgcn_global_load_lds(                                          \
        (const __attribute__((address_space(1))) void*)(gp),                   \
        (__attribute__((address_space(3))) void*)(lp), 16, 0, 0)

// ---------------- CSR build ----------------
__global__ void k_count(const int* __restrict__ dst, int* __restrict__ deg, int E) {
    int e = blockIdx.x * blockDim.x + threadIdx.x;
    if (e < E) atomicAdd(&deg[dst[e]], 1);
}

__global__ void k_scan_block(const int* __restrict__ deg, int* __restrict__ off,
                             int* __restrict__ bsum, int n) {
    __shared__ int s[256];
    int t = threadIdx.x;
    int base = blockIdx.x * 1024 + t * 4;
    int v[4];
#pragma unroll
    for (int i = 0; i < 4; i++) v[i] = (base + i < n) ? deg[base + i] : 0;
    int sum = v[0] + v[1] + v[2] + v[3];
    int val = sum;
    s[t] = val;
    __syncthreads();
    for (int o = 1; o < 256; o <<= 1) {
        int x = (t >= o) ? s[t - o] : 0;
        __syncthreads();
        val += x;
        s[t] = val;
        __syncthreads();
    }
    int run = val - sum;
#pragma unroll
    for (int i = 0; i < 4; i++) {
        if (base + i < n) off[base + i] = run;
        run += v[i];
    }
    if (t == 255) bsum[blockIdx.x] = val;
}

// exclusive scan of bsum, wave-parallel (was: 1 thread x 49 dependent L2 RTs)
__global__ void k_scan_bsum(int* __restrict__ bsum, int nb) {
    int lane = threadIdx.x;  // 64 threads
    int carry = 0;
    for (int start = 0; start < nb; start += 64) {
        int i = start + lane;
        int orig = (i < nb) ? bsum[i] : 0;
        int v = orig;
#pragma unroll
        for (int o = 1; o < 64; o <<= 1) {
            int u = __shfl_up(v, o, 64);
            if (lane >= o) v += u;
        }
        if (i < nb) bsum[i] = carry + v - orig;
        carry += __shfl(v, 63, 64);
    }
}

__global__ void k_scan_add(int* __restrict__ off, const int* __restrict__ bsum, int n) {
    int t = threadIdx.x;
    int base = blockIdx.x * 1024 + t * 4;
    int add = bsum[blockIdx.x];
#pragma unroll
    for (int i = 0; i < 4; i++)
        if (base + i < n) off[base + i] += add;
}

__global__ void k_fill(const int* __restrict__ src, const int* __restrict__ dst,
                       const int* __restrict__ off, int* __restrict__ cur,
                       int* __restrict__ eidx, int E) {
    int e = blockIdx.x * blockDim.x + threadIdx.x;
    if (e < E) {
        int d = dst[e];
        int p = atomicAdd(&cur[d], 1);
        eidx[off[d] + p] = src[e];
    }
}

// ---------------- precision-split prep ----------------
__global__ void k_prepX(const float* __restrict__ x, u16* __restrict__ hi,
                        u16* __restrict__ lo, int n32) {
    int i = blockIdx.x * blockDim.x + threadIdx.x;  // over n*32 float4s
    if (i >= n32) return;
    float4 v = ((const float4*)x)[i];
    float h0 = bf2f(f2bf(v.x)), h1 = bf2f(f2bf(v.y)), h2 = bf2f(f2bf(v.z)), h3 = bf2f(f2bf(v.w));
    uint2 hp, lp;
    hp.x = pack2(h0, h1); hp.y = pack2(h2, h3);
    lp.x = pack2(v.x - h0, v.y - h1); lp.y = pack2(v.z - h2, v.w - h3);
    ((uint2*)hi)[i] = hp;
    ((uint2*)lo)[i] = lp;
}

// all 3 layers' W -> Bt hi/lo planes, packed [layer][hi|lo][128*256]
__global__ void k_prepW3(const float* __restrict__ Ws0, const float* __restrict__ Wn0,
                         const float* __restrict__ Ws1, const float* __restrict__ Wn1,
                         const float* __restrict__ Ws2, const float* __restrict__ Wn2,
                         u16* __restrict__ Bt) {
    int idx = blockIdx.x * blockDim.x + threadIdx.x;  // 3*128*256
    if (idx >= 3 * 128 * 256) return;
    int layer = idx >> 15;
    int within = idx & 32767;
    int col = within >> 8;
    int k = within & 255;
    const float* Ws = (layer == 0) ? Ws0 : (layer == 1) ? Ws1 : Ws2;
    const float* Wn = (layer == 0) ? Wn0 : (layer == 1) ? Wn1 : Wn2;
    int fout = (layer == 2) ? 47 : 128;
    float v = 0.f;
    if (col < fout) v = (k < 128) ? Ws[k * fout + col] : Wn[(k - 128) * fout + col];
    u16 h = f2bf(v);
    Bt[layer * 65536 + within] = h;
    Bt[layer * 65536 + 32768 + within] = f2bf(v - bf2f(h));
}

// ---------------- fused aggregate + MFMA GEMM ----------------
// block = 64 nodes. phase1: 4 waves x 16 nodes gather-mean (hi plane, 256B rows,
// 16-deep MLP) -> LDS hi/lo planes (row stride 136 u16 breaks bank conflicts).
// phase2: K=256 bf16x3 MFMA; kk<128 self (GLDS-staged), kk>=128 neigh (from LDS).
#define NPAD 136
__global__ __launch_bounds__(256) void k_sage(
    const u16* __restrict__ Phi, const u16* __restrict__ Plo,
    const int* __restrict__ eidx, const int* __restrict__ off,
    const int* __restrict__ deg, const u16* __restrict__ Bthi,
    const u16* __restrict__ Btlo, const float* __restrict__ bias,
    float* __restrict__ out_f32, u16* __restrict__ out_hi,
    u16* __restrict__ out_lo, int n, int fout, int relu) {
    __shared__ u16 sNh[64 * NPAD];
    __shared__ u16 sNl[64 * NPAD];
    __shared__ u16 sAhi[64 * 32];
    __shared__ u16 sAlo[64 * 32];
    __shared__ u16 sBhi[128 * 32];
    __shared__ u16 sBlo[128 * 32];

    int t = threadIdx.x;
    int w = t >> 6;
    int lane = t & 63;
    int wr = w >> 1, wc = w & 1;
    size_t row0 = (size_t)blockIdx.x * 64;

    // ---- phase 1: aggregate 16 nodes per wave ----
    {
        const unsigned* h1 = (const unsigned*)Phi;  // 2 bf16 feats per word
        unsigned* nh32 = (unsigned*)sNh;
        unsigned* nl32 = (unsigned*)sNl;
        for (int i = 0; i < 16; i++) {
            int row = w * 16 + i;
            size_t node = row0 + row;
            float a0 = 0.f, a1 = 0.f;
            if (node < (size_t)n) {
                int cnt = deg[node];
                int base = off[node];
                float2 acc = make_float2(0.f, 0.f);
                for (int j = 0; j < cnt; j += 16) {
                    int s[16];
                    float m[16];
#pragma unroll
                    for (int u = 0; u < 16; u++) {
                        int jj = j + u;
                        s[u] = eidx[base + (jj < cnt ? jj : 0)];
                        m[u] = (jj < cnt) ? 1.f : 0.f;
                    }
                    unsigned v[16];
#pragma unroll
                    for (int u = 0; u < 16; u++) v[u] = h1[(size_t)s[u] * 64 + lane];
#pragma unroll
                    for (int u = 0; u < 16; u++) {
                        acc.x = fmaf(m[u], bf2f((u16)(v[u] & 0xffffu)), acc.x);
                        acc.y = fmaf(m[u], bf2f((u16)(v[u] >> 16)), acc.y);
                    }
                }
                int cd = deg[node];
                float iv = 1.0f / (float)(cd > 1 ? cd : 1);
                a0 = acc.x * iv;
                a1 = acc.y * iv;
            }
            float h0 = bf2f(f2bf(a0)), h1v = bf2f(f2bf(a1));
            nh32[row * (NPAD / 2) + lane] = pack2(a0, a1);
            nl32[row * (NPAD / 2) + lane] = pack2(a0 - h0, a1 - h1v);
        }
    }

    // ---- phase 2: MFMA K-loop ----
    f32x4 acc[2][4];
#pragma unroll
    for (int r = 0; r < 2; r++)
#pragma unroll
        for (int c = 0; c < 4; c++) acc[r][c] = (f32x4){0.f, 0.f, 0.f, 0.f};

    for (int kk = 0; kk < 256; kk += 32) {
        __syncthreads();
        if (kk < 128) {
            int r = w * 16 + (lane >> 2);
            int cb = (lane & 3) * 8;
            GLDS16(Phi + (row0 + r) * 128 + kk + cb, &sAhi[r * 32 + cb]);
            GLDS16(Plo + (row0 + r) * 128 + kk + cb, &sAlo[r * 32 + cb]);
        }
#pragma unroll
        for (int i = 0; i < 2; i++) {
            int c = w * 32 + i * 16 + (lane >> 2);
            int cb = (lane & 3) * 8;
            GLDS16(Bthi + (size_t)c * 256 + kk + cb, &sBhi[c * 32 + cb]);
            GLDS16(Btlo + (size_t)c * 256 + kk + cb, &sBlo[c * 32 + cb]);
        }
        __syncthreads();

        bf16x8 a_hi[2], a_lo[2], b_hi[4], b_lo[4];
        int q8 = (lane >> 4) * 8;
        if (kk < 128) {
#pragma unroll
            for (int r = 0; r < 2; r++) {
                int ad = (wr * 32 + r * 16 + (lane & 15)) * 32 + q8;
                a_hi[r] = *(const bf16x8*)&sAhi[ad];
                a_lo[r] = *(const bf16x8*)&sAlo[ad];
            }
        } else {
            int kc2 = kk - 128;
#pragma unroll
            for (int r = 0; r < 2; r++) {
                int ad = (wr * 32 + r * 16 + (lane & 15)) * NPAD + kc2 + q8;
                a_hi[r] = *(const bf16x8*)&sNh[ad];
                a_lo[r] = *(const bf16x8*)&sNl[ad];
            }
        }
#pragma unroll
        for (int c = 0; c < 4; c++) {
            int ad = (wc * 64 + c * 16 + (lane & 15)) * 32 + q8;
            b_hi[c] = *(const bf16x8*)&sBhi[ad];
            b_lo[c] = *(const bf16x8*)&sBlo[ad];
        }
#pragma unroll
        for (int r = 0; r < 2; r++)
#pragma unroll
            for (int c = 0; c < 4; c++) {
                acc[r][c] = __builtin_amdgcn_mfma_f32_16x16x32_bf16(
                    a_hi[r], b_hi[c], acc[r][c], 0, 0, 0);
                acc[r][c] = __builtin_amdgcn_mfma_f32_16x16x32_bf16(
                    a_hi[r], b_lo[c], acc[r][c], 0, 0, 0);
                acc[r][c] = __builtin_amdgcn_mfma_f32_16x16x32_bf16(
                    a_lo[r], b_hi[c], acc[r][c], 0, 0, 0);
            }
    }

    // epilogue: C/D layout col=lane&15, row=quad*4+reg
    int quad = lane >> 4;
    int lcol = lane & 15;
#pragma unroll
    for (int r = 0; r < 2; r++) {
#pragma unroll
        for (int c = 0; c < 4; c++) {
            int col = wc * 64 + c * 16 + lcol;
            float bv = (col < fout) ? bias[col] : 0.f;
#pragma unroll
            for (int g = 0; g < 4; g++) {
                size_t row = row0 + wr * 32 + r * 16 + quad * 4 + g;
                if (row >= (size_t)n || col >= fout) continue;
                float v = acc[r][c][g] + bv;
                if (relu) v = v > 0.f ? v : 0.f;
                if (out_f32) out_f32[row * fout + col] = v;
                if (out_hi) {
                    u16 h = f2bf(v);
                    out_hi[row * 128 + col] = h;
                    out_lo[row * 128 + col] = f2bf(v - bf2f(h));
                }
            }
        }
    }
}

extern "C" void kernel_launch(void* const* d_in, const int* in_sizes, int n_in,
                              void* d_out, int out_size, void* d_ws, size_t ws_size,
                              hipStream_t stream) {
    const float* x = (const float*)d_in[0];
    const int* src = (const int*)d_in[1];
    const int* dst = (const int*)d_in[2];
    const float* Ws0 = (const float*)d_in[3];
    const float* Wn0 = (const float*)d_in[4];
    const float* b0 = (const float*)d_in[5];
    const float* Ws1 = (const float*)d_in[6];
    const float* Wn1 = (const float*)d_in[7];
    const float* b1 = (const float*)d_in[8];
    const float* Ws2 = (const float*)d_in[9];
    const float* Wn2 = (const float*)d_in[10];
    const float* b2 = (const float*)d_in[11];
    float* out = (float*)d_out;

    const int N = in_sizes[0] / 128;
    const int E = in_sizes[1];
    const int Npad = ((N + 63) / 64) * 64;

    // ---- workspace layout (bytes) ----
    char* p = (char*)d_ws;
    u16* P0hi = (u16*)p; p += (size_t)Npad * 128 * 2;  // x planes, then h1 planes
    u16* P0lo = (u16*)p; p += (size_t)Npad * 128 * 2;
    u16* P1hi = (u16*)p; p += (size_t)Npad * 128 * 2;  // h0 planes
    u16* P1lo = (u16*)p; p += (size_t)Npad * 128 * 2;
    u16* Bt = (u16*)p; p += 3 * 2 * 128 * 256 * 2;     // [layer][hi|lo][32768]
    int* deg = (int*)p; p += (size_t)N * 4;
    int* cur = (int*)p; p += (size_t)N * 4;            // adjacent to deg: one memset
    int* off = (int*)p; p += (size_t)N * 4;
    int* eidx = (int*)p; p += (size_t)E * 4;
    int* bsum = (int*)p;

    const int nbE = (E + THREADS - 1) / THREADS;
    const int nbScan = (N + 1023) / 1024;
    const int nbGemm = (N + 63) / 64;
    const int nbPX = (N * 32 + THREADS - 1) / THREADS;
    const int nbPW = (3 * 128 * 256 + THREADS - 1) / THREADS;

    hipMemsetAsync(deg, 0, (size_t)2 * N * sizeof(int), stream);  // deg + cur

    k_count<<<nbE, THREADS, 0, stream>>>(dst, deg, E);
    k_scan_block<<<nbScan, 256, 0, stream>>>(deg, off, bsum, N);
    k_scan_bsum<<<1, 64, 0, stream>>>(bsum, nbScan);
    k_scan_add<<<nbScan, 256, 0, stream>>>(off, bsum, N);
    k_fill<<<nbE, THREADS, 0, stream>>>(src, dst, off, cur, eidx, E);

    k_prepX<<<nbPX, THREADS, 0, stream>>>(x, P0hi, P0lo, N * 32);
    k_prepW3<<<nbPW, THREADS, 0, stream>>>(Ws0, Wn0, Ws1, Wn1, Ws2, Wn2, Bt);

    // layer 0: x planes -> h0 planes (P1)
    k_sage<<<nbGemm, 256, 0, stream>>>(P0hi, P0lo, eidx, off, deg,
                                       Bt + 0 * 65536, Bt + 0 * 65536 + 32768, b0,
                                       (float*)nullptr, P1hi, P1lo, N, 128, 1);
    // layer 1: h0 planes -> h1 planes (reuse P0)
    k_sage<<<nbGemm, 256, 0, stream>>>(P1hi, P1lo, eidx, off, deg,
                                       Bt + 1 * 65536, Bt + 1 * 65536 + 32768, b1,
                                       (float*)nullptr, P0hi, P0lo, N, 128, 1);
    // layer 2: h1 planes -> out (C=47, fp32, no relu)
    k_sage<<<nbGemm, 256, 0, stream>>>(P0hi, P0lo, eidx, off, deg,
                                       Bt + 2 * 65536, Bt + 2 * 65536 + 32768, b2,
                                       out, (u16*)nullptr, (u16*)nullptr, N, 47, 0);
}

// Round 6
// 309.244 us; speedup vs baseline: 1.3660x; 1.3660x over previous
//
#include <hip/hip_runtime.h>
#include <hip/hip_bf16.h>

// GraphSAGE 3-layer forward.
// CSR build -> prep bf16 hi/lo planes -> per layer:
//   aggregate (split kernel): gather bf16 HI-plane rows; one wave = 2 nodes,
//     half-wave x uint2 = full 256B row per half; 8-deep chunks -> 16 rows in
//     flight per wave; fp32 mean; emit hi/lo planes.
//   GEMM: MFMA bf16x3 split (fp32-quality), fused self+neigh K=256.

#define THREADS 256

typedef unsigned short u16;
typedef __attribute__((ext_vector_type(8))) short bf16x8;
typedef __attribute__((ext_vector_type(4))) float f32x4;

__device__ inline u16 f2bf(float f) {
    union { float f; unsigned u; } v; v.f = f;
    unsigned r = (v.u + 0x7FFFu + ((v.u >> 16) & 1u)) >> 16;
    return (u16)r;
}
__device__ inline float bf2f(u16 b) {
    union { unsigned u; float f; } v; v.u = ((unsigned)b) << 16;
    return v.f;
}
__device__ inline unsigned pack2(float a, float b) {
    return (unsigned)f2bf(a) | ((unsigned)f2bf(b) << 16);
}

#define GLDS16(gp, lp)                                                         \
    __builtin_amdgcn_global_load_lds(                                          \
        (const __attribute__((address_space(1))) void*)(gp),                   \
        (__attribute__((address_space(3))) void*)(lp), 16, 0, 0)

// ---------------- CSR build ----------------
__global__ void k_count(const int* __restrict__ dst, int* __restrict__ deg, int E) {
    int e = blockIdx.x * blockDim.x + threadIdx.x;
    if (e < E) atomicAdd(&deg[dst[e]], 1);
}

__global__ void k_scan_block(const int* __restrict__ deg, int* __restrict__ off,
                             int* __restrict__ bsum, int n) {
    __shared__ int s[256];
    int t = threadIdx.x;
    int base = blockIdx.x * 1024 + t * 4;
    int v[4];
#pragma unroll
    for (int i = 0; i < 4; i++) v[i] = (base + i < n) ? deg[base + i] : 0;
    int sum = v[0] + v[1] + v[2] + v[3];
    int val = sum;
    s[t] = val;
    __syncthreads();
    for (int o = 1; o < 256; o <<= 1) {
        int x = (t >= o) ? s[t - o] : 0;
        __syncthreads();
        val += x;
        s[t] = val;
        __syncthreads();
    }
    int run = val - sum;
#pragma unroll
    for (int i = 0; i < 4; i++) {
        if (base + i < n) off[base + i] = run;
        run += v[i];
    }
    if (t == 255) bsum[blockIdx.x] = val;
}

// exclusive scan of bsum, wave-parallel (was: 1 thread x dependent L2 RTs)
__global__ void k_scan_bsum(int* __restrict__ bsum, int nb) {
    int lane = threadIdx.x;  // 64 threads
    int carry = 0;
    for (int start = 0; start < nb; start += 64) {
        int i = start + lane;
        int orig = (i < nb) ? bsum[i] : 0;
        int v = orig;
#pragma unroll
        for (int o = 1; o < 64; o <<= 1) {
            int u = __shfl_up(v, o, 64);
            if (lane >= o) v += u;
        }
        if (i < nb) bsum[i] = carry + v - orig;
        carry += __shfl(v, 63, 64);
    }
}

__global__ void k_scan_add(int* __restrict__ off, const int* __restrict__ bsum, int n) {
    int t = threadIdx.x;
    int base = blockIdx.x * 1024 + t * 4;
    int add = bsum[blockIdx.x];
#pragma unroll
    for (int i = 0; i < 4; i++)
        if (base + i < n) off[base + i] += add;
}

__global__ void k_fill(const int* __restrict__ src, const int* __restrict__ dst,
                       const int* __restrict__ off, int* __restrict__ cur,
                       int* __restrict__ eidx, int E) {
    int e = blockIdx.x * blockDim.x + threadIdx.x;
    if (e < E) {
        int d = dst[e];
        int p = atomicAdd(&cur[d], 1);
        eidx[off[d] + p] = src[e];
    }
}

// ---------------- precision-split prep ----------------
__global__ void k_prepX(const float* __restrict__ x, u16* __restrict__ hi,
                        u16* __restrict__ lo, int n32) {
    int i = blockIdx.x * blockDim.x + threadIdx.x;  // over n*32 float4s
    if (i >= n32) return;
    float4 v = ((const float4*)x)[i];
    float h0 = bf2f(f2bf(v.x)), h1 = bf2f(f2bf(v.y)), h2 = bf2f(f2bf(v.z)), h3 = bf2f(f2bf(v.w));
    uint2 hp, lp;
    hp.x = pack2(h0, h1); hp.y = pack2(h2, h3);
    lp.x = pack2(v.x - h0, v.y - h1); lp.y = pack2(v.z - h2, v.w - h3);
    ((uint2*)hi)[i] = hp;
    ((uint2*)lo)[i] = lp;
}

// all 3 layers' W -> Bt hi/lo planes, packed [layer][hi|lo][128*256]
__global__ void k_prepW3(const float* __restrict__ Ws0, const float* __restrict__ Wn0,
                         const float* __restrict__ Ws1, const float* __restrict__ Wn1,
                         const float* __restrict__ Ws2, const float* __restrict__ Wn2,
                         u16* __restrict__ Bt) {
    int idx = blockIdx.x * blockDim.x + threadIdx.x;  // 3*128*256
    if (idx >= 3 * 128 * 256) return;
    int layer = idx >> 15;
    int within = idx & 32767;
    int col = within >> 8;
    int k = within & 255;
    const float* Ws = (layer == 0) ? Ws0 : (layer == 1) ? Ws1 : Ws2;
    const float* Wn = (layer == 0) ? Wn0 : (layer == 1) ? Wn1 : Wn2;
    int fout = (layer == 2) ? 47 : 128;
    float v = 0.f;
    if (col < fout) v = (k < 128) ? Ws[k * fout + col] : Wn[(k - 128) * fout + col];
    u16 h = f2bf(v);
    Bt[layer * 65536 + within] = h;
    Bt[layer * 65536 + 32768 + within] = f2bf(v - bf2f(h));
}

// ---------------- aggregation ----------------
// one wave = 2 nodes; half-wave (32 lanes) x uint2 (4 feats) = full 256B row.
// 8-deep masked chunks -> 16 rows in flight per wave. fp32 accumulate.
__global__ void k_aggregate(const u16* __restrict__ hi_in, const int* __restrict__ eidx,
                            const int* __restrict__ off, const int* __restrict__ deg,
                            u16* __restrict__ mhi, u16* __restrict__ mlo, int n) {
    int wv = blockIdx.x * 4 + (threadIdx.x >> 6);
    int lane = threadIdx.x & 63;
    int half = lane >> 5;
    int hl = lane & 31;
    int node = wv * 2 + half;
    if (node >= n) return;
    int cnt = deg[node];
    int base = off[node];
    const uint2* h2 = (const uint2*)hi_in;  // row = 32 uint2
    float4 acc = make_float4(0.f, 0.f, 0.f, 0.f);
    for (int j = 0; j < cnt; j += 8) {
        int s[8];
        float m[8];
#pragma unroll
        for (int u = 0; u < 8; u++) {
            int jj = j + u;
            s[u] = eidx[base + (jj < cnt ? jj : 0)];
            m[u] = (jj < cnt) ? 1.f : 0.f;
        }
        uint2 v[8];
#pragma unroll
        for (int u = 0; u < 8; u++) v[u] = h2[(size_t)s[u] * 32 + hl];
#pragma unroll
        for (int u = 0; u < 8; u++) {
            acc.x = fmaf(m[u], bf2f((u16)(v[u].x & 0xffffu)), acc.x);
            acc.y = fmaf(m[u], bf2f((u16)(v[u].x >> 16)), acc.y);
            acc.z = fmaf(m[u], bf2f((u16)(v[u].y & 0xffffu)), acc.z);
            acc.w = fmaf(m[u], bf2f((u16)(v[u].y >> 16)), acc.w);
        }
    }
    float iv = 1.0f / (float)(cnt > 1 ? cnt : 1);
    float a0 = acc.x * iv, a1 = acc.y * iv, a2 = acc.z * iv, a3 = acc.w * iv;
    float r0 = bf2f(f2bf(a0)), r1 = bf2f(f2bf(a1)), r2 = bf2f(f2bf(a2)), r3 = bf2f(f2bf(a3));
    uint2 hp, lp;
    hp.x = pack2(a0, a1); hp.y = pack2(a2, a3);
    lp.x = pack2(a0 - r0, a1 - r1); lp.y = pack2(a2 - r2, a3 - r3);
    ((uint2*)mhi)[(size_t)node * 32 + hl] = hp;
    ((uint2*)mlo)[(size_t)node * 32 + hl] = lp;
}

// ---------------- MFMA GEMM (bf16x3 split) ----------------
__global__ __launch_bounds__(256) void k_gemm_mfma(
    const u16* __restrict__ Ahi_s, const u16* __restrict__ Alo_s,
    const u16* __restrict__ Ahi_n, const u16* __restrict__ Alo_n,
    const u16* __restrict__ Bthi, const u16* __restrict__ Btlo,
    const float* __restrict__ bias, float* __restrict__ out_f32,
    u16* __restrict__ out_hi, u16* __restrict__ out_lo, int n, int fout, int relu) {
    __shared__ u16 sAhi[64 * 32];
    __shared__ u16 sAlo[64 * 32];
    __shared__ u16 sBhi[128 * 32];
    __shared__ u16 sBlo[128 * 32];

    int t = threadIdx.x;
    int w = t >> 6;
    int lane = t & 63;
    int wr = w >> 1, wc = w & 1;
    size_t row0 = (size_t)blockIdx.x * 64;

    f32x4 acc[2][4];
#pragma unroll
    for (int r = 0; r < 2; r++)
#pragma unroll
        for (int c = 0; c < 4; c++) acc[r][c] = (f32x4){0.f, 0.f, 0.f, 0.f};

    for (int kk = 0; kk < 256; kk += 32) {
        const u16* Phi = (kk < 128) ? Ahi_s : Ahi_n;
        const u16* Plo = (kk < 128) ? Alo_s : Alo_n;
        int kc = kk & 127;
        __syncthreads();
        {
            int r = w * 16 + (lane >> 2);
            int cb = (lane & 3) * 8;
            GLDS16(Phi + (row0 + r) * 128 + kc + cb, &sAhi[r * 32 + cb]);
            GLDS16(Plo + (row0 + r) * 128 + kc + cb, &sAlo[r * 32 + cb]);
        }
#pragma unroll
        for (int i = 0; i < 2; i++) {
            int c = w * 32 + i * 16 + (lane >> 2);
            int cb = (lane & 3) * 8;
            GLDS16(Bthi + (size_t)c * 256 + kk + cb, &sBhi[c * 32 + cb]);
            GLDS16(Btlo + (size_t)c * 256 + kk + cb, &sBlo[c * 32 + cb]);
        }
        __syncthreads();

        bf16x8 a_hi[2], a_lo[2], b_hi[4], b_lo[4];
        int q8 = (lane >> 4) * 8;
#pragma unroll
        for (int r = 0; r < 2; r++) {
            int ad = (wr * 32 + r * 16 + (lane & 15)) * 32 + q8;
            a_hi[r] = *(const bf16x8*)&sAhi[ad];
            a_lo[r] = *(const bf16x8*)&sAlo[ad];
        }
#pragma unroll
        for (int c = 0; c < 4; c++) {
            int ad = (wc * 64 + c * 16 + (lane & 15)) * 32 + q8;
            b_hi[c] = *(const bf16x8*)&sBhi[ad];
            b_lo[c] = *(const bf16x8*)&sBlo[ad];
        }
#pragma unroll
        for (int r = 0; r < 2; r++)
#pragma unroll
            for (int c = 0; c < 4; c++) {
                acc[r][c] = __builtin_amdgcn_mfma_f32_16x16x32_bf16(
                    a_hi[r], b_hi[c], acc[r][c], 0, 0, 0);
                acc[r][c] = __builtin_amdgcn_mfma_f32_16x16x32_bf16(
                    a_hi[r], b_lo[c], acc[r][c], 0, 0, 0);
                acc[r][c] = __builtin_amdgcn_mfma_f32_16x16x32_bf16(
                    a_lo[r], b_hi[c], acc[r][c], 0, 0, 0);
            }
    }

    // epilogue: C/D layout col=lane&15, row=quad*4+reg
    int quad = lane >> 4;
    int lcol = lane & 15;
#pragma unroll
    for (int r = 0; r < 2; r++) {
#pragma unroll
        for (int c = 0; c < 4; c++) {
            int col = wc * 64 + c * 16 + lcol;
            float bv = (col < fout) ? bias[col] : 0.f;
#pragma unroll
            for (int g = 0; g < 4; g++) {
                size_t row = row0 + wr * 32 + r * 16 + quad * 4 + g;
                if (row >= (size_t)n || col >= fout) continue;
                float v = acc[r][c][g] + bv;
                if (relu) v = v > 0.f ? v : 0.f;
                if (out_f32) out_f32[row * fout + col] = v;
                if (out_hi) {
                    u16 h = f2bf(v);
                    out_hi[row * 128 + col] = h;
                    out_lo[row * 128 + col] = f2bf(v - bf2f(h));
                }
            }
        }
    }
}

extern "C" void kernel_launch(void* const* d_in, const int* in_sizes, int n_in,
                              void* d_out, int out_size, void* d_ws, size_t ws_size,
                              hipStream_t stream) {
    const float* x = (const float*)d_in[0];
    const int* src = (const int*)d_in[1];
    const int* dst = (const int*)d_in[2];
    const float* Ws0 = (const float*)d_in[3];
    const float* Wn0 = (const float*)d_in[4];
    const float* b0 = (const float*)d_in[5];
    const float* Ws1 = (const float*)d_in[6];
    const float* Wn1 = (const float*)d_in[7];
    const float* b1 = (const float*)d_in[8];
    const float* Ws2 = (const float*)d_in[9];
    const float* Wn2 = (const float*)d_in[10];
    const float* b2 = (const float*)d_in[11];
    float* out = (float*)d_out;

    const int N = in_sizes[0] / 128;
    const int E = in_sizes[1];
    const int Npad = ((N + 63) / 64) * 64;

    // ---- workspace layout (bytes) ----
    char* p = (char*)d_ws;
    u16* P0hi = (u16*)p; p += (size_t)Npad * 128 * 2;  // x planes, then h1 planes
    u16* P0lo = (u16*)p; p += (size_t)Npad * 128 * 2;
    u16* P1hi = (u16*)p; p += (size_t)Npad * 128 * 2;  // h0 planes
    u16* P1lo = (u16*)p; p += (size_t)Npad * 128 * 2;
    u16* Mhi = (u16*)p; p += (size_t)Npad * 128 * 2;   // msum planes
    u16* Mlo = (u16*)p; p += (size_t)Npad * 128 * 2;
    u16* Bt = (u16*)p; p += 3 * 2 * 128 * 256 * 2;     // [layer][hi|lo][32768]
    int* deg = (int*)p; p += (size_t)N * 4;
    int* cur = (int*)p; p += (size_t)N * 4;            // adjacent to deg: one memset
    int* off = (int*)p; p += (size_t)N * 4;
    int* eidx = (int*)p; p += (size_t)E * 4;
    int* bsum = (int*)p;

    const int nbE = (E + THREADS - 1) / THREADS;
    const int nbScan = (N + 1023) / 1024;
    const int nbAgg = (N + 7) / 8;                     // 4 waves x 2 nodes per block
    const int nbGemm = (N + 63) / 64;
    const int nbPX = (N * 32 + THREADS - 1) / THREADS;
    const int nbPW = (3 * 128 * 256 + THREADS - 1) / THREADS;

    hipMemsetAsync(deg, 0, (size_t)2 * N * sizeof(int), stream);  // deg + cur

    k_count<<<nbE, THREADS, 0, stream>>>(dst, deg, E);
    k_scan_block<<<nbScan, 256, 0, stream>>>(deg, off, bsum, N);
    k_scan_bsum<<<1, 64, 0, stream>>>(bsum, nbScan);
    k_scan_add<<<nbScan, 256, 0, stream>>>(off, bsum, N);
    k_fill<<<nbE, THREADS, 0, stream>>>(src, dst, off, cur, eidx, E);

    k_prepX<<<nbPX, THREADS, 0, stream>>>(x, P0hi, P0lo, N * 32);
    k_prepW3<<<nbPW, THREADS, 0, stream>>>(Ws0, Wn0, Ws1, Wn1, Ws2, Wn2, Bt);

    // layer 0: x planes -> h0 planes (P1)
    k_aggregate<<<nbAgg, 256, 0, stream>>>(P0hi, eidx, off, deg, Mhi, Mlo, N);
    k_gemm_mfma<<<nbGemm, 256, 0, stream>>>(P0hi, P0lo, Mhi, Mlo,
                                            Bt + 0 * 65536, Bt + 0 * 65536 + 32768, b0,
                                            (float*)nullptr, P1hi, P1lo, N, 128, 1);
    // layer 1: h0 planes -> h1 planes (reuse P0)
    k_aggregate<<<nbAgg, 256, 0, stream>>>(P1hi, eidx, off, deg, Mhi, Mlo, N);
    k_gemm_mfma<<<nbGemm, 256, 0, stream>>>(P1hi, P1lo, Mhi, Mlo,
                                            Bt + 1 * 65536, Bt + 1 * 65536 + 32768, b1,
                                            (float*)nullptr, P0hi, P0lo, N, 128, 1);
    // layer 2: h1 planes -> out (C=47, fp32, no relu)
    k_aggregate<<<nbAgg, 256, 0, stream>>>(P0hi, eidx, off, deg, Mhi, Mlo, N);
    k_gemm_mfma<<<nbGemm, 256, 0, stream>>>(P0hi, P0lo, Mhi, Mlo,
                                            Bt + 2 * 65536, Bt + 2 * 65536 + 32768, b2,
                                            out, (u16*)nullptr, (u16*)nullptr, N, 47, 0);
}